// Round 3
// baseline (1483.920 us; speedup 1.0000x reference)
//
#include <hip/hip_runtime.h>
#include <cstdint>
#include <cstddef>

#define T_TOKENS 4096
#define DIM      1024
#define INTER    1408
#define NEXP     16
#define SINTER   2816

typedef uint32_t u32;
typedef uint16_t u16;

using s8v = __attribute__((ext_vector_type(8))) short;   // 8 bf16 (4 VGPRs)
using f4v = __attribute__((ext_vector_type(4))) float;   // MFMA accumulator

__device__ __forceinline__ u16 f2bf(float f) {
  u32 u = __float_as_uint(f);
  return (u16)((u + 0x7fffu + ((u >> 16) & 1u)) >> 16);  // RNE
}
__device__ __forceinline__ u32 pack2(float a, float b) {
  return (u32)f2bf(a) | ((u32)f2bf(b) << 16);
}

// async global->LDS, 16B/lane. LDS dest is wave-uniform base + lane*16.
__device__ __forceinline__ void load_lds16(const u16* g, u16* l) {
  __builtin_amdgcn_global_load_lds((const __attribute__((address_space(1))) void*)g,
                                   (__attribute__((address_space(3))) void*)l,
                                   16, 0, 0);
}

// ---------------- x: fp32 -> bf16 (row-major, elementwise) ------------------
__global__ __launch_bounds__(256)
void cvt_x(const float* __restrict__ in, u16* __restrict__ out) {
  const int i = (blockIdx.x * 256 + threadIdx.x) * 8;
  float4 a = *(const float4*)(in + i);
  float4 b = *(const float4*)(in + i + 4);
  uint4 o;
  o.x = pack2(a.x, a.y); o.y = pack2(a.z, a.w);
  o.z = pack2(b.x, b.y); o.w = pack2(b.z, b.w);
  *(uint4*)(out + i) = o;
}

// ------------- weights: [Z][K][N] fp32 -> [Z][N][K] bf16 (transpose) --------
__global__ __launch_bounds__(256)
void transpose_cvt(const float* __restrict__ in, u16* __restrict__ out,
                   int K, int N) {
  const size_t eoff = (size_t)blockIdx.z * K * N;
  const int n0 = blockIdx.x * 64, k0 = blockIdx.y * 64;
  __shared__ u16 t[64][72];   // row stride 144B = 9*16B: 16B-aligned vector reads

  const int tid = threadIdx.x;
  {
    const int r = tid >> 4, c4 = (tid & 15) * 4;
    const float* src = in + eoff + (size_t)k0 * N + n0;
#pragma unroll
    for (int i = 0; i < 4; i++) {
      int row = r + i * 16;
      float4 v = *(const float4*)(src + (size_t)row * N + c4);
      t[c4 + 0][row] = f2bf(v.x);
      t[c4 + 1][row] = f2bf(v.y);
      t[c4 + 2][row] = f2bf(v.z);
      t[c4 + 3][row] = f2bf(v.w);
    }
  }
  __syncthreads();
  {
    const int r = tid >> 3, cc = (tid & 7) * 8;
    u16* dst = out + eoff + (size_t)n0 * K + k0;
#pragma unroll
    for (int i = 0; i < 2; i++) {
      int row = r + i * 32;
      uint4 v = *(const uint4*)&t[row][cc];
      *(uint4*)(dst + (size_t)row * K + cc) = v;
    }
  }
}

// --------- Gate phase 1: logits -> softmax -> per-token top2 (no atomics) ---
__global__ __launch_bounds__(256)
void gate_logits(const float* __restrict__ x, const float* __restrict__ gw,
                 const float* __restrict__ gb,
                 int* __restrict__ g_e, float* __restrict__ g_w)
{
  const int tok  = blockIdx.x * 4 + (threadIdx.x >> 6);
  const int lane = threadIdx.x & 63;
  const int e = lane & 15, s = lane >> 4;
  const float* xr = x + (size_t)tok * DIM;

  float acc = 0.f;
#pragma unroll 8
  for (int i = 0; i < DIM / 4; i++) {
    const int k = i * 4 + s;
    acc = fmaf(xr[k], gw[i * 64 + lane], acc);   // gw[k*NEXP + e]
  }
  acc += __shfl_xor(acc, 16, 64);
  acc += __shfl_xor(acc, 32, 64);
  const float logit = acc + gb[e];

  float mx = logit;
#pragma unroll
  for (int o = 1; o < 16; o <<= 1) mx = fmaxf(mx, __shfl_xor(mx, o, 64));
  float p = __expf(logit - mx);
  float sum = p;
#pragma unroll
  for (int o = 1; o < 16; o <<= 1) sum += __shfl_xor(sum, o, 64);
  p /= sum;

  // top-1
  float m0 = p; int i0 = e;
#pragma unroll
  for (int o = 1; o < 16; o <<= 1) {
    float om = __shfl_xor(m0, o, 64); int oi = __shfl_xor(i0, o, 64);
    if (om > m0 || (om == m0 && oi < i0)) { m0 = om; i0 = oi; }
  }
  // top-2
  float p1 = (e == i0) ? -1.f : p;
  float m1 = p1; int i1 = e;
#pragma unroll
  for (int o = 1; o < 16; o <<= 1) {
    float om = __shfl_xor(m1, o, 64); int oi = __shfl_xor(i1, o, 64);
    if (om > m1 || (om == m1 && oi < i1)) { m1 = om; i1 = oi; }
  }
  if (lane == 0) {
    g_e[tok * 2 + 0] = i0;  g_e[tok * 2 + 1] = i1;
    g_w[tok * 2 + 0] = m0;  g_w[tok * 2 + 1] = m1;
  }
}

// --------- Gate phase 2: single-block scan + deterministic scatter ----------
__global__ __launch_bounds__(256)
void route_build(const int* __restrict__ g_e,
                 int* __restrict__ offsets,
                 int* __restrict__ tok_slot, int* __restrict__ slot_of)
{
  __shared__ int hist[256][NEXP + 1];   // +1 pad: breaks 16-stride bank aliasing
  __shared__ int base[NEXP + 1];
  const int tid = threadIdx.x;
  const int TPT = T_TOKENS / 256;       // tokens per thread
  const int t0 = tid * TPT;

#pragma unroll
  for (int e = 0; e < NEXP; e++) hist[tid][e] = 0;
  for (int t = t0; t < t0 + TPT; t++) {
    hist[tid][g_e[t * 2 + 0]]++;
    hist[tid][g_e[t * 2 + 1]]++;
  }
  __syncthreads();
  if (tid < NEXP) {                     // per-expert exclusive scan over threads
    int run = 0;
    for (int i = 0; i < 256; i++) { int v = hist[i][tid]; hist[i][tid] = run; run += v; }
    base[tid] = run;                    // total for expert tid
  }
  __syncthreads();
  if (tid == 0) {                       // expert-base exclusive scan
    int run = 0;
#pragma unroll
    for (int e = 0; e < NEXP; e++) { int c = base[e]; base[e] = run; offsets[e] = run; run += c; }
    base[NEXP] = run; offsets[NEXP] = run;
  }
  __syncthreads();
  for (int t = t0; t < t0 + TPT; t++) {
#pragma unroll
    for (int k = 0; k < 2; k++) {
      const int e = g_e[t * 2 + k];
      const int slot = base[e] + hist[tid][e]++;   // prefix cell as running ctr
      tok_slot[slot] = t;
      slot_of[t * 2 + k] = slot;                   // inverse map for combine
    }
  }
}

// ------------- Up: act = silu(X@W1+b1)*(X@W3+b3), 128x128 tile, BK=64 -------
// A operand: per-lane global->register loads (no LDS staging, no gather in the
// barrier path). B1/B3: global_load_lds double-buffered, [128][64] tiles with
// T2 XOR swizzle (pre-swizzled global source, linear LDS dest, XOR on read):
// 2-way banked ds_read_b128 instead of 16-way. 16 K-steps, 1 barrier each.
template<bool GATHER>
__global__ __launch_bounds__(256, 2)
void ffn_up3(const u16* __restrict__ xbf,
             const u16* __restrict__ w1t, const float* __restrict__ b1p,
             const u16* __restrict__ w3t, const float* __restrict__ b3p,
             int N,
             const int* __restrict__ offsets, const int* __restrict__ tok_slot,
             u16* __restrict__ act)
{
  const int e = GATHER ? blockIdx.z : 0;
  int rowbase = 0, count = T_TOKENS;
  if constexpr (GATHER) { rowbase = offsets[e]; count = offsets[e + 1] - rowbase; }
  const int m0 = blockIdx.x * 128;
  if (m0 >= count) return;
  const int n0 = blockIdx.y * 128;

  const u16* W1 = w1t + (size_t)e * N * DIM;
  const u16* W3 = w3t + (size_t)e * N * DIM;
  const float* B1 = b1p + (size_t)e * N;
  const float* B3 = b3p + (size_t)e * N;

  __shared__ u16 sB1[2][128 * 64];   // 32 KB
  __shared__ u16 sB3[2][128 * 64];   // 32 KB

  const int tid = threadIdx.x, lane = tid & 63, w = tid >> 6;
  const int ln = lane & 15, q = lane >> 4;
  const int wm = (w & 1) * 64, wn = (w >> 1) * 64;

  // ---- B staging: instr i covers rows [i*32 + w*8, +8) of the [128][64] tile.
  // LDS dest linear (lane*16B); global source col chunk XOR'd with row&7 so the
  // read-side XOR recovers G[row][k] (involution).
  const int srow = w * 8 + (lane >> 3);               // row&7 == lane>>3
  const int scol = ((lane & 7) ^ (lane >> 3)) * 8;    // pre-swizzled source chunk
  const u16* b1ptr[4]; const u16* b3ptr[4]; int ldoffB[4];
#pragma unroll
  for (int i = 0; i < 4; i++) {
    const int row = i * 32 + srow;
    ldoffB[i] = row * 64 + (lane & 7) * 8;            // == uniform + lane*8 elems
    b1ptr[i] = W1 + (size_t)(n0 + row) * DIM + scol;
    b3ptr[i] = W3 + (size_t)(n0 + row) * DIM + scol;
  }

  // ---- A: direct per-lane global loads. af[i] = A[m0+wm+16i+ln][k0 + q*8 ..+8)
  const u16* pA[4];
#pragma unroll
  for (int i = 0; i < 4; i++) {
    int arow = m0 + wm + i * 16 + ln; if (arow > count - 1) arow = count - 1;
    const int tok = GATHER ? tok_slot[rowbase + arow] : arow;
    pA[i] = xbf + (size_t)tok * DIM + q * 8;
  }

  // read-side swizzled LDS offsets (elements); key = (ln&7)*8
  const int pbBase = (wn + ln) * 64;
  const int swz0 = (q * 8) ^ ((ln & 7) * 8);          // kk = 0
  const int swz1 = (q * 8 + 32) ^ ((ln & 7) * 8);     // kk = 1

  f4v acc1[4][4] = {};
  f4v acc3[4][4] = {};

  auto stage = [&](int buf, int k0) {
#pragma unroll
    for (int i = 0; i < 4; i++) {
      load_lds16(b1ptr[i] + k0, &sB1[buf][ldoffB[i]]);
      load_lds16(b3ptr[i] + k0, &sB3[buf][ldoffB[i]]);
    }
  };

  stage(0, 0);
  __syncthreads();
  int cur = 0;
  for (int k0 = 64; k0 <= DIM; k0 += 64) {
    if (k0 < DIM) stage(cur ^ 1, k0);   // prefetch next K-tile (overlaps MFMA)
    const int kb = k0 - 64;
#pragma unroll
    for (int kk = 0; kk < 2; kk++) {    // two 32-wide K halves
      const int sw = kk ? swz1 : swz0;
      s8v af[4];
#pragma unroll
      for (int i = 0; i < 4; i++) af[i] = *(const s8v*)(pA[i] + kb + kk * 32);
      const u16* pb1 = &sB1[cur][pbBase + sw];
      const u16* pb3 = &sB3[cur][pbBase + sw];
#pragma unroll
      for (int j = 0; j < 4; j++) {
        s8v bf1 = *(const s8v*)(pb1 + j * 1024);      // row wn+ln+16j
#pragma unroll
        for (int i = 0; i < 4; i++)
          acc1[i][j] = __builtin_amdgcn_mfma_f32_16x16x32_bf16(af[i], bf1, acc1[i][j], 0, 0, 0);
        s8v bf3 = *(const s8v*)(pb3 + j * 1024);
#pragma unroll
        for (int i = 0; i < 4; i++)
          acc3[i][j] = __builtin_amdgcn_mfma_f32_16x16x32_bf16(af[i], bf3, acc3[i][j], 0, 0, 0);
      }
    }
    __syncthreads();                    // next-tile loads done; cur reusable
    cur ^= 1;
  }

  float bb1[4], bb3[4];
#pragma unroll
  for (int j = 0; j < 4; j++) {
    const int col = n0 + wn + j * 16 + ln;
    bb1[j] = B1[col]; bb3[j] = B3[col];
  }
#pragma unroll
  for (int i = 0; i < 4; i++) {
#pragma unroll
    for (int r = 0; r < 4; r++) {
      const int row = m0 + wm + i * 16 + q * 4 + r;  // D: row=quad*4+reg
      if (row >= count) continue;
      u16* ap = act + (size_t)(rowbase + row) * N + n0 + wn;
#pragma unroll
      for (int j = 0; j < 4; j++) {
        float h = acc1[i][j][r] + bb1[j];
        float g = acc3[i][j][r] + bb3[j];
        float sv = 1.f / (1.f + __expf(-h));
        ap[j * 16 + ln] = f2bf(h * sv * g);             // D: col=lane&15
      }
    }
  }
}

// ------------- Down: Y = act @ W2T^T (+b2); A reg-loaded, B LDS dbuf --------
template<bool ROUTED>
__global__ __launch_bounds__(256, 3)
void ffn_down3(const u16* __restrict__ act, int KA,
               const u16* __restrict__ w2t, const float* __restrict__ b2p,
               const int* __restrict__ offsets,
               float* __restrict__ outp)
{
  const int e = ROUTED ? blockIdx.z : 0;
  int rowbase = 0, count = T_TOKENS;
  if constexpr (ROUTED) { rowbase = offsets[e]; count = offsets[e + 1] - rowbase; }
  const int m0 = blockIdx.x * 128;
  if (m0 >= count) return;
  const int n0 = blockIdx.y * 128;

  const u16* W2 = w2t + (size_t)e * DIM * KA;   // [DIM][KA] bf16
  const float* B2 = b2p + (size_t)e * DIM;

  __shared__ u16 sB[2][128 * 64];   // 32 KB total

  const int tid = threadIdx.x, lane = tid & 63, w = tid >> 6;
  const int ln = lane & 15, q = lane >> 4;
  const int wm = (w & 1) * 64, wn = (w >> 1) * 64;

  const int srow = w * 8 + (lane >> 3);
  const int scol = ((lane & 7) ^ (lane >> 3)) * 8;
  const u16* bptr[4]; int ldoffB[4];
#pragma unroll
  for (int i = 0; i < 4; i++) {
    const int row = i * 32 + srow;
    ldoffB[i] = row * 64 + (lane & 7) * 8;
    bptr[i] = W2 + (size_t)(n0 + row) * KA + scol;
  }

  // A: compacted act rows — contiguous, no gather
  const u16* pA[4];
#pragma unroll
  for (int i = 0; i < 4; i++) {
    int arow = m0 + wm + i * 16 + ln; if (arow > count - 1) arow = count - 1;
    pA[i] = act + (size_t)(rowbase + arow) * KA + q * 8;
  }

  const int pbBase = (wn + ln) * 64;
  const int swz0 = (q * 8) ^ ((ln & 7) * 8);
  const int swz1 = (q * 8 + 32) ^ ((ln & 7) * 8);

  f4v acc[4][4] = {};

  auto stage = [&](int buf, int k0) {
#pragma unroll
    for (int i = 0; i < 4; i++)
      load_lds16(bptr[i] + k0, &sB[buf][ldoffB[i]]);
  };

  stage(0, 0);
  __syncthreads();
  int cur = 0;
  for (int k0 = 64; k0 <= KA; k0 += 64) {
    if (k0 < KA) stage(cur ^ 1, k0);
    const int kb = k0 - 64;
#pragma unroll
    for (int kk = 0; kk < 2; kk++) {
      const int sw = kk ? swz1 : swz0;
      s8v af[4];
#pragma unroll
      for (int i = 0; i < 4; i++) af[i] = *(const s8v*)(pA[i] + kb + kk * 32);
      const u16* pb = &sB[cur][pbBase + sw];
#pragma unroll
      for (int j = 0; j < 4; j++) {
        s8v bf = *(const s8v*)(pb + j * 1024);
#pragma unroll
        for (int i = 0; i < 4; i++)
          acc[i][j] = __builtin_amdgcn_mfma_f32_16x16x32_bf16(af[i], bf, acc[i][j], 0, 0, 0);
      }
    }
    __syncthreads();
    cur ^= 1;
  }

  float bb[4];
#pragma unroll
  for (int j = 0; j < 4; j++) bb[j] = B2[n0 + wn + j * 16 + ln];

#pragma unroll
  for (int i = 0; i < 4; i++) {
#pragma unroll
    for (int r = 0; r < 4; r++) {
      const int row = m0 + wm + i * 16 + q * 4 + r;
      if (row >= count) continue;
      float* orow = outp + (size_t)(rowbase + row) * DIM + n0 + wn;
#pragma unroll
      for (int j = 0; j < 4; j++)
        orow[j * 16 + ln] = acc[i][j][r] + bb[j];
    }
  }
}

// ------------- Combine: out[t] += w0*R[s0] + w1*R[s1] (atomic-free) ---------
__global__ __launch_bounds__(256)
void combine(const float* __restrict__ R, const int* __restrict__ slot_of,
             const float* __restrict__ g_w, float* __restrict__ out)
{
  const int t = blockIdx.x;
  const int c = threadIdx.x * 4;
  const int s0 = slot_of[t * 2 + 0], s1 = slot_of[t * 2 + 1];
  const float w0 = g_w[t * 2 + 0],  w1 = g_w[t * 2 + 1];
  float4 a = *(const float4*)(R + (size_t)s0 * DIM + c);
  float4 b = *(const float4*)(R + (size_t)s1 * DIM + c);
  float* op = out + (size_t)t * DIM + c;
  float4 o = *(const float4*)op;
  o.x += w0 * a.x + w1 * b.x;
  o.y += w0 * a.y + w1 * b.y;
  o.z += w0 * a.z + w1 * b.z;
  o.w += w0 * a.w + w1 * b.w;
  *(float4*)op = o;
}

extern "C" void kernel_launch(void* const* d_in, const int* in_sizes, int n_in,
                              void* d_out, int out_size, void* d_ws, size_t ws_size,
                              hipStream_t stream)
{
  const float* x   = (const float*)d_in[0];
  const float* gw  = (const float*)d_in[1];
  const float* gb  = (const float*)d_in[2];
  const float* w1  = (const float*)d_in[3];
  const float* b1  = (const float*)d_in[4];
  const float* w3  = (const float*)d_in[5];
  const float* b3  = (const float*)d_in[6];
  const float* w2  = (const float*)d_in[7];
  const float* b2  = (const float*)d_in[8];
  const float* sw1 = (const float*)d_in[9];
  const float* sb1 = (const float*)d_in[10];
  const float* sw3 = (const float*)d_in[11];
  const float* sb3 = (const float*)d_in[12];
  const float* sw2 = (const float*)d_in[13];
  const float* sb2 = (const float*)d_in[14];
  float* out = (float*)d_out;

  char* ws = (char*)d_ws;
  size_t off = 0;
  auto alloc = [&](size_t bytes) -> char* {
    off = (off + 255) & ~(size_t)255;
    char* p = ws + off;
    off += bytes;
    return p;
  };
  int*   offsets  = (int*)  alloc((NEXP + 1) * 4);
  int*   g_e      = (int*)  alloc((size_t)T_TOKENS * 2 * 4);
  float* g_w      = (float*)alloc((size_t)T_TOKENS * 2 * 4);
  int*   tok_slot = (int*)  alloc((size_t)T_TOKENS * 2 * 4);
  int*   slot_of  = (int*)  alloc((size_t)T_TOKENS * 2 * 4);
  u16*   xbf      = (u16*)  alloc((size_t)T_TOKENS * DIM * 2);
  u16*   w1t      = (u16*)  alloc((size_t)NEXP * INTER * DIM * 2);
  u16*   w3t      = (u16*)  alloc((size_t)NEXP * INTER * DIM * 2);
  u16*   w2t      = (u16*)  alloc((size_t)NEXP * DIM * INTER * 2);
  u16*   sw1t     = (u16*)  alloc((size_t)SINTER * DIM * 2);
  u16*   sw3t     = (u16*)  alloc((size_t)SINTER * DIM * 2);
  u16*   sw2t     = (u16*)  alloc((size_t)DIM * SINTER * 2);
  u16*   A_act    = (u16*)  alloc((size_t)T_TOKENS * 2 * INTER * 2);
  u16*   S_act    = (u16*)  alloc((size_t)T_TOKENS * SINTER * 2);
  // Rbuf (32 MB fp32) ALIASES w1t (46 MB): w1t dead after routed ffn_up3;
  // Rbuf first written by routed ffn_down3 (later, same stream).
  float* Rbuf     = (float*)w1t;
  (void)ws_size; (void)in_sizes; (void)n_in; (void)out_size;

  // ---- routing (atomic-free) ----
  gate_logits<<<T_TOKENS / 4, 256, 0, stream>>>(x, gw, gb, g_e, g_w);
  route_build<<<1, 256, 0, stream>>>(g_e, offsets, tok_slot, slot_of);

  // ---- weight/activation conversion (bf16, weights transposed to [N][K]) ---
  cvt_x<<<(T_TOKENS * DIM) / (256 * 8), 256, 0, stream>>>(x, xbf);
  transpose_cvt<<<dim3(INTER / 64, DIM / 64, NEXP), 256, 0, stream>>>(w1, w1t, DIM, INTER);
  transpose_cvt<<<dim3(INTER / 64, DIM / 64, NEXP), 256, 0, stream>>>(w3, w3t, DIM, INTER);
  transpose_cvt<<<dim3(DIM / 64, INTER / 64, NEXP), 256, 0, stream>>>(w2, w2t, INTER, DIM);
  transpose_cvt<<<dim3(SINTER / 64, DIM / 64, 1), 256, 0, stream>>>(sw1, sw1t, DIM, SINTER);
  transpose_cvt<<<dim3(SINTER / 64, DIM / 64, 1), 256, 0, stream>>>(sw3, sw3t, DIM, SINTER);
  transpose_cvt<<<dim3(DIM / 64, SINTER / 64, 1), 256, 0, stream>>>(sw2, sw2t, SINTER, DIM);

  // ---- shared expert (plain store initializes out) ----
  ffn_up3<false><<<dim3(T_TOKENS / 128, SINTER / 128, 1), 256, 0, stream>>>(
      xbf, sw1t, sb1, sw3t, sb3, SINTER, nullptr, nullptr, S_act);
  ffn_down3<false><<<dim3(T_TOKENS / 128, DIM / 128, 1), 256, 0, stream>>>(
      S_act, SINTER, sw2t, sb2, nullptr, out);

  // ---- routed experts (compacted GEMMs, spread grid; combine adds scatter) -
  ffn_up3<true><<<dim3(T_TOKENS / 128, INTER / 128, NEXP), 256, 0, stream>>>(
      xbf, w1t, b1, w3t, b3, INTER, offsets, tok_slot, A_act);
  ffn_down3<true><<<dim3(T_TOKENS / 128, DIM / 128, NEXP), 256, 0, stream>>>(
      A_act, INTER, w2t, b2, offsets, Rbuf);
  combine<<<T_TOKENS, 256, 0, stream>>>(Rbuf, slot_of, g_w, out);
}

// Round 4
// 694.146 us; speedup vs baseline: 2.1378x; 2.1378x over previous
//
#include <hip/hip_runtime.h>
#include <cstdint>
#include <cstddef>

#define T_TOKENS 4096
#define DIM      1024
#define INTER    1408
#define NEXP     16
#define SINTER   2816

typedef uint32_t u32;
typedef uint16_t u16;

using s8v = __attribute__((ext_vector_type(8))) short;   // 8 bf16 (4 VGPRs)
using f4v = __attribute__((ext_vector_type(4))) float;   // MFMA accumulator

__device__ __forceinline__ u16 f2bf(float f) {
  u32 u = __float_as_uint(f);
  return (u16)((u + 0x7fffu + ((u >> 16) & 1u)) >> 16);  // RNE
}
__device__ __forceinline__ u32 pack2(float a, float b) {
  return (u32)f2bf(a) | ((u32)f2bf(b) << 16);
}

// async global->LDS, 16B/lane. LDS dest is wave-uniform base + lane*16.
__device__ __forceinline__ void load_lds16(const u16* g, u16* l) {
  __builtin_amdgcn_global_load_lds((const __attribute__((address_space(1))) void*)g,
                                   (__attribute__((address_space(3))) void*)l,
                                   16, 0, 0);
}

// ---------------- x: fp32 -> bf16 (row-major, elementwise) ------------------
__global__ __launch_bounds__(256)
void cvt_x(const float* __restrict__ in, u16* __restrict__ out) {
  const int i = (blockIdx.x * 256 + threadIdx.x) * 8;
  float4 a = *(const float4*)(in + i);
  float4 b = *(const float4*)(in + i + 4);
  uint4 o;
  o.x = pack2(a.x, a.y); o.y = pack2(a.z, a.w);
  o.z = pack2(b.x, b.y); o.w = pack2(b.z, b.w);
  *(uint4*)(out + i) = o;
}

// ------------- weights: [Z][K][N] fp32 -> [Z][N][K] bf16 (transpose) --------
__global__ __launch_bounds__(256)
void transpose_cvt(const float* __restrict__ in, u16* __restrict__ out,
                   int K, int N) {
  const size_t eoff = (size_t)blockIdx.z * K * N;
  const int n0 = blockIdx.x * 64, k0 = blockIdx.y * 64;
  __shared__ u16 t[64][72];   // row stride 144B = 9*16B: 16B-aligned vector reads

  const int tid = threadIdx.x;
  {
    const int r = tid >> 4, c4 = (tid & 15) * 4;
    const float* src = in + eoff + (size_t)k0 * N + n0;
#pragma unroll
    for (int i = 0; i < 4; i++) {
      int row = r + i * 16;
      float4 v = *(const float4*)(src + (size_t)row * N + c4);
      t[c4 + 0][row] = f2bf(v.x);
      t[c4 + 1][row] = f2bf(v.y);
      t[c4 + 2][row] = f2bf(v.z);
      t[c4 + 3][row] = f2bf(v.w);
    }
  }
  __syncthreads();
  {
    const int r = tid >> 3, cc = (tid & 7) * 8;
    u16* dst = out + eoff + (size_t)n0 * K + k0;
#pragma unroll
    for (int i = 0; i < 2; i++) {
      int row = r + i * 32;
      uint4 v = *(const uint4*)&t[row][cc];
      *(uint4*)(dst + (size_t)row * K + cc) = v;
    }
  }
}

// --------- Gate phase 1: logits -> softmax -> per-token top2 (no atomics) ---
__global__ __launch_bounds__(256)
void gate_logits(const float* __restrict__ x, const float* __restrict__ gw,
                 const float* __restrict__ gb,
                 int* __restrict__ g_e, float* __restrict__ g_w)
{
  const int tok  = blockIdx.x * 4 + (threadIdx.x >> 6);
  const int lane = threadIdx.x & 63;
  const int e = lane & 15, s = lane >> 4;
  const float* xr = x + (size_t)tok * DIM;

  float acc = 0.f;
#pragma unroll 8
  for (int i = 0; i < DIM / 4; i++) {
    const int k = i * 4 + s;
    acc = fmaf(xr[k], gw[i * 64 + lane], acc);   // gw[k*NEXP + e]
  }
  acc += __shfl_xor(acc, 16, 64);
  acc += __shfl_xor(acc, 32, 64);
  const float logit = acc + gb[e];

  float mx = logit;
#pragma unroll
  for (int o = 1; o < 16; o <<= 1) mx = fmaxf(mx, __shfl_xor(mx, o, 64));
  float p = __expf(logit - mx);
  float sum = p;
#pragma unroll
  for (int o = 1; o < 16; o <<= 1) sum += __shfl_xor(sum, o, 64);
  p /= sum;

  // top-1
  float m0 = p; int i0 = e;
#pragma unroll
  for (int o = 1; o < 16; o <<= 1) {
    float om = __shfl_xor(m0, o, 64); int oi = __shfl_xor(i0, o, 64);
    if (om > m0 || (om == m0 && oi < i0)) { m0 = om; i0 = oi; }
  }
  // top-2
  float p1 = (e == i0) ? -1.f : p;
  float m1 = p1; int i1 = e;
#pragma unroll
  for (int o = 1; o < 16; o <<= 1) {
    float om = __shfl_xor(m1, o, 64); int oi = __shfl_xor(i1, o, 64);
    if (om > m1 || (om == m1 && oi < i1)) { m1 = om; i1 = oi; }
  }
  if (lane == 0) {
    g_e[tok * 2 + 0] = i0;  g_e[tok * 2 + 1] = i1;
    g_w[tok * 2 + 0] = m0;  g_w[tok * 2 + 1] = m1;
  }
}

// --------- Gate phase 2: single-block scan + deterministic scatter ----------
__global__ __launch_bounds__(256)
void route_build(const int* __restrict__ g_e,
                 int* __restrict__ offsets,
                 int* __restrict__ tok_slot, int* __restrict__ slot_of)
{
  __shared__ int hist[256][NEXP + 1];   // +1 pad: breaks 16-stride bank aliasing
  __shared__ int base[NEXP + 1];
  const int tid = threadIdx.x;
  const int TPT = T_TOKENS / 256;       // tokens per thread
  const int t0 = tid * TPT;

#pragma unroll
  for (int e = 0; e < NEXP; e++) hist[tid][e] = 0;
  for (int t = t0; t < t0 + TPT; t++) {
    hist[tid][g_e[t * 2 + 0]]++;
    hist[tid][g_e[t * 2 + 1]]++;
  }
  __syncthreads();
  if (tid < NEXP) {                     // per-expert exclusive scan over threads
    int run = 0;
    for (int i = 0; i < 256; i++) { int v = hist[i][tid]; hist[i][tid] = run; run += v; }
    base[tid] = run;                    // total for expert tid
  }
  __syncthreads();
  if (tid == 0) {                       // expert-base exclusive scan
    int run = 0;
#pragma unroll
    for (int e = 0; e < NEXP; e++) { int c = base[e]; base[e] = run; offsets[e] = run; run += c; }
    base[NEXP] = run; offsets[NEXP] = run;
  }
  __syncthreads();
  for (int t = t0; t < t0 + TPT; t++) {
#pragma unroll
    for (int k = 0; k < 2; k++) {
      const int e = g_e[t * 2 + k];
      const int slot = base[e] + hist[tid][e]++;   // prefix cell as running ctr
      tok_slot[slot] = t;
      slot_of[t * 2 + k] = slot;                   // inverse map for combine
    }
  }
}

// ------------- Up: act = silu(X@W1+b1)*(X@W3+b3), 128x128 tile, BK=32 -------
// Round-0 proven staging layout (A,B1,B3 all global_load_lds; compute reads
// LDS only) + double buffer: stage(k+1) issued BEFORE compute(k), ONE barrier
// per K-step (round 0 had two). Spread dim3 grid, no XCD pinning (r2 lesson),
// no swizzle (r3 lesson: conflicts off critical path at 2-phase).
template<bool GATHER>
__global__ __launch_bounds__(256, 2)
void ffn_up4(const u16* __restrict__ xbf,
             const u16* __restrict__ w1t, const float* __restrict__ b1p,
             const u16* __restrict__ w3t, const float* __restrict__ b3p,
             int N,
             const int* __restrict__ offsets, const int* __restrict__ tok_slot,
             u16* __restrict__ act)
{
  const int e = GATHER ? blockIdx.z : 0;
  int rowbase = 0, count = T_TOKENS;
  if constexpr (GATHER) { rowbase = offsets[e]; count = offsets[e + 1] - rowbase; }
  const int m0 = blockIdx.y * 128;
  if (m0 >= count) return;
  const int n0 = blockIdx.x * 128;

  const u16* W1 = w1t + (size_t)e * N * DIM;
  const u16* W3 = w3t + (size_t)e * N * DIM;
  const float* B1 = b1p + (size_t)e * N;
  const float* B3 = b3p + (size_t)e * N;

  __shared__ u16 sA[2][128 * 32];
  __shared__ u16 sB1[2][128 * 32];
  __shared__ u16 sB3[2][128 * 32];

  const int tid = threadIdx.x;
  const int lane = tid & 63;
  const int w = tid >> 6;

  // staging: instr i covers rows [i*64 + w*16, +16); lane -> (row, 16B k-chunk)
  const int kc8 = (lane & 3) * 8;
  const u16* aptr[2]; const u16* b1ptr[2]; const u16* b3ptr[2];
  int ldoff[2];
#pragma unroll
  for (int i = 0; i < 2; i++) {
    const int row = i * 64 + w * 16 + (lane >> 2);
    ldoff[i] = i * 2048 + w * 512 + lane * 8;        // == row*32 + kc8
    int arow = m0 + row; if (arow > count - 1) arow = count - 1;  // clamp pads
    const int tok = GATHER ? tok_slot[rowbase + arow] : arow;
    aptr[i]  = xbf + (size_t)tok * DIM + kc8;
    const int brow = n0 + row;
    b1ptr[i] = W1 + (size_t)brow * DIM + kc8;
    b3ptr[i] = W3 + (size_t)brow * DIM + kc8;
  }

  const int ln = lane & 15, q = lane >> 4;
  const int wm = (w & 1) * 64, wn = (w >> 1) * 64;
  const int paOff = (wm + ln) * 32 + q * 8;
  const int pbOff = (wn + ln) * 32 + q * 8;

  f4v acc1[4][4] = {};
  f4v acc3[4][4] = {};

  auto stage = [&](int buf, int k0) {
#pragma unroll
    for (int i = 0; i < 2; i++) {
      load_lds16(aptr[i]  + k0, &sA[buf][ldoff[i]]);
      load_lds16(b1ptr[i] + k0, &sB1[buf][ldoff[i]]);
      load_lds16(b3ptr[i] + k0, &sB3[buf][ldoff[i]]);
    }
  };

  stage(0, 0);
  __syncthreads();                       // drains vmcnt(0): buf0 ready
  int cur = 0;
  for (int k0 = 32; k0 <= DIM; k0 += 32) {
    if (k0 < DIM) stage(cur ^ 1, k0);    // prefetch next K-step (overlaps MFMA)

    const u16* pa  = sA[cur]  + paOff;
    const u16* pb1 = sB1[cur] + pbOff;
    const u16* pb3 = sB3[cur] + pbOff;
    s8v af[4];
#pragma unroll
    for (int i = 0; i < 4; i++) af[i] = *(const s8v*)(pa + i * 512);
#pragma unroll
    for (int j = 0; j < 4; j++) {
      s8v bf1 = *(const s8v*)(pb1 + j * 512);
#pragma unroll
      for (int i = 0; i < 4; i++)
        acc1[i][j] = __builtin_amdgcn_mfma_f32_16x16x32_bf16(af[i], bf1, acc1[i][j], 0, 0, 0);
      s8v bf3 = *(const s8v*)(pb3 + j * 512);
#pragma unroll
      for (int i = 0; i < 4; i++)
        acc3[i][j] = __builtin_amdgcn_mfma_f32_16x16x32_bf16(af[i], bf3, acc3[i][j], 0, 0, 0);
    }
    __syncthreads();   // next-buf loads drained + cur safe to overwrite next it
    cur ^= 1;
  }

  float bb1[4], bb3[4];
#pragma unroll
  for (int j = 0; j < 4; j++) {
    const int col = n0 + wn + j * 16 + ln;
    bb1[j] = B1[col]; bb3[j] = B3[col];
  }
#pragma unroll
  for (int i = 0; i < 4; i++) {
#pragma unroll
    for (int r = 0; r < 4; r++) {
      const int row = m0 + wm + i * 16 + q * 4 + r;  // D: row=quad*4+reg
      if (row >= count) continue;
      u16* ap = act + (size_t)(rowbase + row) * N + n0 + wn;
#pragma unroll
      for (int j = 0; j < 4; j++) {
        float h = acc1[i][j][r] + bb1[j];
        float g = acc3[i][j][r] + bb3[j];
        float sv = 1.f / (1.f + __expf(-h));
        ap[j * 16 + ln] = f2bf(h * sv * g);             // D: col=lane&15
      }
    }
  }
}

// ------------- Down: Y = act @ W2T^T (+b2); plain store (R buf if ROUTED) ---
template<bool ROUTED>
__global__ __launch_bounds__(256, 2)
void ffn_down4(const u16* __restrict__ act, int KA,
               const u16* __restrict__ w2t, const float* __restrict__ b2p,
               const int* __restrict__ offsets,
               float* __restrict__ outp)
{
  const int e = ROUTED ? blockIdx.z : 0;
  int rowbase = 0, count = T_TOKENS;
  if constexpr (ROUTED) { rowbase = offsets[e]; count = offsets[e + 1] - rowbase; }
  const int m0 = blockIdx.y * 128;
  if (m0 >= count) return;
  const int n0 = blockIdx.x * 128;

  const u16* W2 = w2t + (size_t)e * DIM * KA;   // [DIM][KA] bf16
  const float* B2 = b2p + (size_t)e * DIM;

  __shared__ u16 sA[2][128 * 32];
  __shared__ u16 sB[2][128 * 32];

  const int tid = threadIdx.x;
  const int lane = tid & 63;
  const int w = tid >> 6;

  const int kc8 = (lane & 3) * 8;
  const u16* aptr[2]; const u16* bptr[2];
  int ldoff[2];
#pragma unroll
  for (int i = 0; i < 2; i++) {
    const int row = i * 64 + w * 16 + (lane >> 2);
    ldoff[i] = i * 2048 + w * 512 + lane * 8;
    int arow = m0 + row; if (arow > count - 1) arow = count - 1;
    aptr[i] = act + (size_t)(rowbase + arow) * KA + kc8;
    bptr[i] = W2 + (size_t)(n0 + row) * KA + kc8;
  }

  const int ln = lane & 15, q = lane >> 4;
  const int wm = (w & 1) * 64, wn = (w >> 1) * 64;
  const int paOff = (wm + ln) * 32 + q * 8;
  const int pbOff = (wn + ln) * 32 + q * 8;

  f4v acc[4][4] = {};

  auto stage = [&](int buf, int k0) {
#pragma unroll
    for (int i = 0; i < 2; i++) {
      load_lds16(aptr[i] + k0, &sA[buf][ldoff[i]]);
      load_lds16(bptr[i] + k0, &sB[buf][ldoff[i]]);
    }
  };

  stage(0, 0);
  __syncthreads();
  int cur = 0;
  for (int k0 = 32; k0 <= KA; k0 += 32) {
    if (k0 < KA) stage(cur ^ 1, k0);

    const u16* pa = sA[cur] + paOff;
    const u16* pb = sB[cur] + pbOff;
    s8v af[4];
#pragma unroll
    for (int i = 0; i < 4; i++) af[i] = *(const s8v*)(pa + i * 512);
#pragma unroll
    for (int j = 0; j < 4; j++) {
      s8v bf = *(const s8v*)(pb + j * 512);
#pragma unroll
      for (int i = 0; i < 4; i++)
        acc[i][j] = __builtin_amdgcn_mfma_f32_16x16x32_bf16(af[i], bf, acc[i][j], 0, 0, 0);
    }
    __syncthreads();
    cur ^= 1;
  }

  float bb[4];
#pragma unroll
  for (int j = 0; j < 4; j++) bb[j] = B2[n0 + wn + j * 16 + ln];

#pragma unroll
  for (int i = 0; i < 4; i++) {
#pragma unroll
    for (int r = 0; r < 4; r++) {
      const int row = m0 + wm + i * 16 + q * 4 + r;
      if (row >= count) continue;
      float* orow = outp + (size_t)(rowbase + row) * DIM + n0 + wn;
#pragma unroll
      for (int j = 0; j < 4; j++)
        orow[j * 16 + ln] = acc[i][j][r] + bb[j];
    }
  }
}

// ------------- Combine: out[t] += w0*R[s0] + w1*R[s1] (atomic-free) ---------
__global__ __launch_bounds__(256)
void combine(const float* __restrict__ R, const int* __restrict__ slot_of,
             const float* __restrict__ g_w, float* __restrict__ out)
{
  const int t = blockIdx.x;
  const int c = threadIdx.x * 4;
  const int s0 = slot_of[t * 2 + 0], s1 = slot_of[t * 2 + 1];
  const float w0 = g_w[t * 2 + 0],  w1 = g_w[t * 2 + 1];
  float4 a = *(const float4*)(R + (size_t)s0 * DIM + c);
  float4 b = *(const float4*)(R + (size_t)s1 * DIM + c);
  float* op = out + (size_t)t * DIM + c;
  float4 o = *(const float4*)op;
  o.x += w0 * a.x + w1 * b.x;
  o.y += w0 * a.y + w1 * b.y;
  o.z += w0 * a.z + w1 * b.z;
  o.w += w0 * a.w + w1 * b.w;
  *(float4*)op = o;
}

extern "C" void kernel_launch(void* const* d_in, const int* in_sizes, int n_in,
                              void* d_out, int out_size, void* d_ws, size_t ws_size,
                              hipStream_t stream)
{
  const float* x   = (const float*)d_in[0];
  const float* gw  = (const float*)d_in[1];
  const float* gb  = (const float*)d_in[2];
  const float* w1  = (const float*)d_in[3];
  const float* b1  = (const float*)d_in[4];
  const float* w3  = (const float*)d_in[5];
  const float* b3  = (const float*)d_in[6];
  const float* w2  = (const float*)d_in[7];
  const float* b2  = (const float*)d_in[8];
  const float* sw1 = (const float*)d_in[9];
  const float* sb1 = (const float*)d_in[10];
  const float* sw3 = (const float*)d_in[11];
  const float* sb3 = (const float*)d_in[12];
  const float* sw2 = (const float*)d_in[13];
  const float* sb2 = (const float*)d_in[14];
  float* out = (float*)d_out;

  char* ws = (char*)d_ws;
  size_t off = 0;
  auto alloc = [&](size_t bytes) -> char* {
    off = (off + 255) & ~(size_t)255;
    char* p = ws + off;
    off += bytes;
    return p;
  };
  int*   offsets  = (int*)  alloc((NEXP + 1) * 4);
  int*   g_e      = (int*)  alloc((size_t)T_TOKENS * 2 * 4);
  float* g_w      = (float*)alloc((size_t)T_TOKENS * 2 * 4);
  int*   tok_slot = (int*)  alloc((size_t)T_TOKENS * 2 * 4);
  int*   slot_of  = (int*)  alloc((size_t)T_TOKENS * 2 * 4);
  u16*   xbf      = (u16*)  alloc((size_t)T_TOKENS * DIM * 2);
  u16*   w1t      = (u16*)  alloc((size_t)NEXP * INTER * DIM * 2);
  u16*   w3t      = (u16*)  alloc((size_t)NEXP * INTER * DIM * 2);
  u16*   w2t      = (u16*)  alloc((size_t)NEXP * DIM * INTER * 2);
  u16*   sw1t     = (u16*)  alloc((size_t)SINTER * DIM * 2);
  u16*   sw3t     = (u16*)  alloc((size_t)SINTER * DIM * 2);
  u16*   sw2t     = (u16*)  alloc((size_t)DIM * SINTER * 2);
  u16*   A_act    = (u16*)  alloc((size_t)T_TOKENS * 2 * INTER * 2);
  u16*   S_act    = (u16*)  alloc((size_t)T_TOKENS * SINTER * 2);
  // Rbuf (32 MB fp32) ALIASES w1t (46 MB): w1t dead after routed ffn_up4;
  // Rbuf first written by routed ffn_down4 (later, same stream).
  float* Rbuf     = (float*)w1t;
  (void)ws_size; (void)in_sizes; (void)n_in; (void)out_size;

  // ---- routing (atomic-free) ----
  gate_logits<<<T_TOKENS / 4, 256, 0, stream>>>(x, gw, gb, g_e, g_w);
  route_build<<<1, 256, 0, stream>>>(g_e, offsets, tok_slot, slot_of);

  // ---- weight/activation conversion (bf16, weights transposed to [N][K]) ---
  cvt_x<<<(T_TOKENS * DIM) / (256 * 8), 256, 0, stream>>>(x, xbf);
  transpose_cvt<<<dim3(INTER / 64, DIM / 64, NEXP), 256, 0, stream>>>(w1, w1t, DIM, INTER);
  transpose_cvt<<<dim3(INTER / 64, DIM / 64, NEXP), 256, 0, stream>>>(w3, w3t, DIM, INTER);
  transpose_cvt<<<dim3(DIM / 64, INTER / 64, NEXP), 256, 0, stream>>>(w2, w2t, INTER, DIM);
  transpose_cvt<<<dim3(SINTER / 64, DIM / 64, 1), 256, 0, stream>>>(sw1, sw1t, DIM, SINTER);
  transpose_cvt<<<dim3(SINTER / 64, DIM / 64, 1), 256, 0, stream>>>(sw3, sw3t, DIM, SINTER);
  transpose_cvt<<<dim3(DIM / 64, SINTER / 64, 1), 256, 0, stream>>>(sw2, sw2t, SINTER, DIM);

  // ---- shared expert (plain store initializes out) ----
  ffn_up4<false><<<dim3(SINTER / 128, T_TOKENS / 128, 1), 256, 0, stream>>>(
      xbf, sw1t, sb1, sw3t, sb3, SINTER, nullptr, nullptr, S_act);
  ffn_down4<false><<<dim3(DIM / 128, T_TOKENS / 128, 1), 256, 0, stream>>>(
      S_act, SINTER, sw2t, sb2, nullptr, out);

  // ---- routed experts (compacted GEMMs, spread grid; combine adds scatter) -
  ffn_up4<true><<<dim3(INTER / 128, T_TOKENS / 128, NEXP), 256, 0, stream>>>(
      xbf, w1t, b1, w3t, b3, INTER, offsets, tok_slot, A_act);
  ffn_down4<true><<<dim3(DIM / 128, T_TOKENS / 128, NEXP), 256, 0, stream>>>(
      A_act, INTER, w2t, b2, offsets, Rbuf);
  combine<<<T_TOKENS, 256, 0, stream>>>(Rbuf, slot_of, g_w, out);
}

// Round 6
// 653.664 us; speedup vs baseline: 2.2702x; 1.0619x over previous
//
#include <hip/hip_runtime.h>
#include <cstdint>
#include <cstddef>

#define T_TOKENS 4096
#define DIM      1024
#define INTER    1408
#define NEXP     16
#define SINTER   2816
#define KD       1408   // uniform K-length for every down-GEMM block

typedef uint32_t u32;
typedef uint16_t u16;

using s8v = __attribute__((ext_vector_type(8))) short;   // 8 bf16 (4 VGPRs)
using f4v = __attribute__((ext_vector_type(4))) float;   // MFMA accumulator

__device__ __forceinline__ u16 f2bf(float f) {
  u32 u = __float_as_uint(f);
  return (u16)((u + 0x7fffu + ((u >> 16) & 1u)) >> 16);  // RNE
}
__device__ __forceinline__ u32 pack2(float a, float b) {
  return (u32)f2bf(a) | ((u32)f2bf(b) << 16);
}

// async global->LDS, 16B/lane. LDS dest is wave-uniform base + lane*16.
__device__ __forceinline__ void load_lds16(const u16* g, u16* l) {
  __builtin_amdgcn_global_load_lds((const __attribute__((address_space(1))) void*)g,
                                   (__attribute__((address_space(3))) void*)l,
                                   16, 0, 0);
}

// ---------------- x: fp32 -> bf16 (row-major, elementwise) ------------------
__global__ __launch_bounds__(256)
void cvt_x(const float* __restrict__ in, u16* __restrict__ out) {
  const int i = (blockIdx.x * 256 + threadIdx.x) * 8;
  float4 a = *(const float4*)(in + i);
  float4 b = *(const float4*)(in + i + 4);
  uint4 o;
  o.x = pack2(a.x, a.y); o.y = pack2(a.z, a.w);
  o.z = pack2(b.x, b.y); o.w = pack2(b.z, b.w);
  *(uint4*)(out + i) = o;
}

// ------- weights: [Z][K][N] fp32 -> [Z][N][K] bf16 (transpose, 2 mats) ------
// z encodes (e, which-matrix): e = z>>1, sel = z&1. Used for w1/w3 (32 z) and
// sw1/sw3 (2 z) merges — halves launch count on the big transposes.
__global__ __launch_bounds__(256)
void transpose_cvt2(const float* __restrict__ in0, const float* __restrict__ in1,
                    u16* __restrict__ out0, u16* __restrict__ out1,
                    int K, int N) {
  const int e = blockIdx.z >> 1, sel = blockIdx.z & 1;
  const float* in = sel ? in1 : in0;
  u16* out = sel ? out1 : out0;
  const size_t eoff = (size_t)e * K * N;
  const int n0 = blockIdx.x * 64, k0 = blockIdx.y * 64;
  __shared__ u16 t[64][72];   // row stride 144B = 9*16B: 16B-aligned vector reads

  const int tid = threadIdx.x;
  {
    const int r = tid >> 4, c4 = (tid & 15) * 4;
    const float* src = in + eoff + (size_t)k0 * N + n0;
#pragma unroll
    for (int i = 0; i < 4; i++) {
      int row = r + i * 16;
      float4 v = *(const float4*)(src + (size_t)row * N + c4);
      t[c4 + 0][row] = f2bf(v.x);
      t[c4 + 1][row] = f2bf(v.y);
      t[c4 + 2][row] = f2bf(v.z);
      t[c4 + 3][row] = f2bf(v.w);
    }
  }
  __syncthreads();
  {
    const int r = tid >> 3, cc = (tid & 7) * 8;
    u16* dst = out + eoff + (size_t)n0 * K + k0;
#pragma unroll
    for (int i = 0; i < 2; i++) {
      int row = r + i * 32;
      uint4 v = *(const uint4*)&t[row][cc];
      *(uint4*)(dst + (size_t)row * K + cc) = v;
    }
  }
}

// single-matrix variant (w2, sw2)
__global__ __launch_bounds__(256)
void transpose_cvt(const float* __restrict__ in, u16* __restrict__ out,
                   int K, int N) {
  const size_t eoff = (size_t)blockIdx.z * K * N;
  const int n0 = blockIdx.x * 64, k0 = blockIdx.y * 64;
  __shared__ u16 t[64][72];

  const int tid = threadIdx.x;
  {
    const int r = tid >> 4, c4 = (tid & 15) * 4;
    const float* src = in + eoff + (size_t)k0 * N + n0;
#pragma unroll
    for (int i = 0; i < 4; i++) {
      int row = r + i * 16;
      float4 v = *(const float4*)(src + (size_t)row * N + c4);
      t[c4 + 0][row] = f2bf(v.x);
      t[c4 + 1][row] = f2bf(v.y);
      t[c4 + 2][row] = f2bf(v.z);
      t[c4 + 3][row] = f2bf(v.w);
    }
  }
  __syncthreads();
  {
    const int r = tid >> 3, cc = (tid & 7) * 8;
    u16* dst = out + eoff + (size_t)n0 * K + k0;
#pragma unroll
    for (int i = 0; i < 2; i++) {
      int row = r + i * 32;
      uint4 v = *(const uint4*)&t[row][cc];
      *(uint4*)(dst + (size_t)row * K + cc) = v;
    }
  }
}

// --------- Gate phase 1: logits -> softmax -> per-token top2 (no atomics) ---
__global__ __launch_bounds__(256)
void gate_logits(const float* __restrict__ x, const float* __restrict__ gw,
                 const float* __restrict__ gb,
                 int* __restrict__ g_e, float* __restrict__ g_w)
{
  const int tok  = blockIdx.x * 4 + (threadIdx.x >> 6);
  const int lane = threadIdx.x & 63;
  const int e = lane & 15, s = lane >> 4;
  const float* xr = x + (size_t)tok * DIM;

  float acc = 0.f;
#pragma unroll 8
  for (int i = 0; i < DIM / 4; i++) {
    const int k = i * 4 + s;
    acc = fmaf(xr[k], gw[i * 64 + lane], acc);   // gw[k*NEXP + e]
  }
  acc += __shfl_xor(acc, 16, 64);
  acc += __shfl_xor(acc, 32, 64);
  const float logit = acc + gb[e];

  float mx = logit;
#pragma unroll
  for (int o = 1; o < 16; o <<= 1) mx = fmaxf(mx, __shfl_xor(mx, o, 64));
  float p = __expf(logit - mx);
  float sum = p;
#pragma unroll
  for (int o = 1; o < 16; o <<= 1) sum += __shfl_xor(sum, o, 64);
  p /= sum;

  // top-1
  float m0 = p; int i0 = e;
#pragma unroll
  for (int o = 1; o < 16; o <<= 1) {
    float om = __shfl_xor(m0, o, 64); int oi = __shfl_xor(i0, o, 64);
    if (om > m0 || (om == m0 && oi < i0)) { m0 = om; i0 = oi; }
  }
  // top-2
  float p1 = (e == i0) ? -1.f : p;
  float m1 = p1; int i1 = e;
#pragma unroll
  for (int o = 1; o < 16; o <<= 1) {
    float om = __shfl_xor(m1, o, 64); int oi = __shfl_xor(i1, o, 64);
    if (om > m1 || (om == m1 && oi < i1)) { m1 = om; i1 = oi; }
  }
  if (lane == 0) {
    g_e[tok * 2 + 0] = i0;  g_e[tok * 2 + 1] = i1;
    g_w[tok * 2 + 0] = m0;  g_w[tok * 2 + 1] = m1;
  }
}

// --------- Gate phase 2: single-block scan + deterministic scatter ----------
__global__ __launch_bounds__(256)
void route_build(const int* __restrict__ g_e,
                 int* __restrict__ offsets,
                 int* __restrict__ tok_slot, int* __restrict__ slot_of)
{
  __shared__ int hist[256][NEXP + 1];   // +1 pad: breaks 16-stride bank aliasing
  __shared__ int base[NEXP + 1];
  const int tid = threadIdx.x;
  const int TPT = T_TOKENS / 256;       // tokens per thread
  const int t0 = tid * TPT;

#pragma unroll
  for (int e = 0; e < NEXP; e++) hist[tid][e] = 0;
  for (int t = t0; t < t0 + TPT; t++) {
    hist[tid][g_e[t * 2 + 0]]++;
    hist[tid][g_e[t * 2 + 1]]++;
  }
  __syncthreads();
  if (tid < NEXP) {                     // per-expert exclusive scan over threads
    int run = 0;
    for (int i = 0; i < 256; i++) { int v = hist[i][tid]; hist[i][tid] = run; run += v; }
    base[tid] = run;                    // total for expert tid
  }
  __syncthreads();
  if (tid == 0) {                       // expert-base exclusive scan
    int run = 0;
#pragma unroll
    for (int e = 0; e < NEXP; e++) { int c = base[e]; base[e] = run; offsets[e] = run; run += c; }
    base[NEXP] = run; offsets[NEXP] = run;
  }
  __syncthreads();
  for (int t = t0; t < t0 + TPT; t++) {
#pragma unroll
    for (int k = 0; k < 2; k++) {
      const int e = g_e[t * 2 + k];
      const int slot = base[e] + hist[tid][e]++;   // prefix cell as running ctr
      tok_slot[slot] = t;
      slot_of[t * 2 + k] = slot;                   // inverse map for combine
    }
  }
}

// ------- Up (MERGED): act = silu(X@W1+b1)*(X@W3+b3), 128x128, BK=32 ---------
// z = 0..NEXP-1: routed expert z (gathered A, N=INTER, writes A_act)
// z = NEXP:      shared expert   (dense A,    N=SINTER, writes S_act)
// Inner loop identical to the r0/r4-verified structure (dbuf, 1 barrier/step).
// Merging lets shared-expert blocks fill the routed tail (machine balance).
__global__ __launch_bounds__(256, 2)
void ffn_up_m(const u16* __restrict__ xbf,
              const u16* __restrict__ w1t, const float* __restrict__ b1p,
              const u16* __restrict__ w3t, const float* __restrict__ b3p,
              const u16* __restrict__ sw1t, const float* __restrict__ sb1,
              const u16* __restrict__ sw3t, const float* __restrict__ sb3,
              const int* __restrict__ offsets, const int* __restrict__ tok_slot,
              u16* __restrict__ A_act, u16* __restrict__ S_act)
{
  const int z = blockIdx.z;
  const bool shr = (z == NEXP);
  int N, count, rowbase = 0;
  const u16 *W1, *W3; const float *B1, *B3; u16* act;
  if (shr) {
    N = SINTER; count = T_TOKENS;
    W1 = sw1t; W3 = sw3t; B1 = sb1; B3 = sb3; act = S_act;
  } else {
    N = INTER; rowbase = offsets[z]; count = offsets[z + 1] - rowbase;
    W1 = w1t + (size_t)z * INTER * DIM; W3 = w3t + (size_t)z * INTER * DIM;
    B1 = b1p + (size_t)z * INTER;       B3 = b3p + (size_t)z * INTER;
    act = A_act;
  }
  const int n0 = blockIdx.x * 128;
  if (n0 >= N) return;                  // routed ghosts beyond INTER
  const int m0 = blockIdx.y * 128;
  if (m0 >= count) return;              // m-tile ghosts

  __shared__ u16 sA[2][128 * 32];
  __shared__ u16 sB1[2][128 * 32];
  __shared__ u16 sB3[2][128 * 32];

  const int tid = threadIdx.x;
  const int lane = tid & 63;
  const int w = tid >> 6;

  // staging: instr i covers rows [i*64 + w*16, +16); lane -> (row, 16B k-chunk)
  const int kc8 = (lane & 3) * 8;
  const u16* aptr[2]; const u16* b1ptr[2]; const u16* b3ptr[2];
  int ldoff[2];
#pragma unroll
  for (int i = 0; i < 2; i++) {
    const int row = i * 64 + w * 16 + (lane >> 2);
    ldoff[i] = i * 2048 + w * 512 + lane * 8;        // == row*32 + kc8
    int arow = m0 + row; if (arow > count - 1) arow = count - 1;  // clamp pads
    const int tok = shr ? arow : tok_slot[rowbase + arow];
    aptr[i]  = xbf + (size_t)tok * DIM + kc8;
    const int brow = n0 + row;
    b1ptr[i] = W1 + (size_t)brow * DIM + kc8;
    b3ptr[i] = W3 + (size_t)brow * DIM + kc8;
  }

  const int ln = lane & 15, q = lane >> 4;
  const int wm = (w & 1) * 64, wn = (w >> 1) * 64;
  const int paOff = (wm + ln) * 32 + q * 8;
  const int pbOff = (wn + ln) * 32 + q * 8;

  f4v acc1[4][4] = {};
  f4v acc3[4][4] = {};

  auto stage = [&](int buf, int k0) {
#pragma unroll
    for (int i = 0; i < 2; i++) {
      load_lds16(aptr[i]  + k0, &sA[buf][ldoff[i]]);
      load_lds16(b1ptr[i] + k0, &sB1[buf][ldoff[i]]);
      load_lds16(b3ptr[i] + k0, &sB3[buf][ldoff[i]]);
    }
  };

  stage(0, 0);
  __syncthreads();                       // buf0 ready
  int cur = 0;
  for (int k0 = 32; k0 <= DIM; k0 += 32) {
    if (k0 < DIM) stage(cur ^ 1, k0);    // prefetch next K-step (overlaps MFMA)

    const u16* pa  = sA[cur]  + paOff;
    const u16* pb1 = sB1[cur] + pbOff;
    const u16* pb3 = sB3[cur] + pbOff;
    s8v af[4];
#pragma unroll
    for (int i = 0; i < 4; i++) af[i] = *(const s8v*)(pa + i * 512);
#pragma unroll
    for (int j = 0; j < 4; j++) {
      s8v bf1 = *(const s8v*)(pb1 + j * 512);
#pragma unroll
      for (int i = 0; i < 4; i++)
        acc1[i][j] = __builtin_amdgcn_mfma_f32_16x16x32_bf16(af[i], bf1, acc1[i][j], 0, 0, 0);
      s8v bf3 = *(const s8v*)(pb3 + j * 512);
#pragma unroll
      for (int i = 0; i < 4; i++)
        acc3[i][j] = __builtin_amdgcn_mfma_f32_16x16x32_bf16(af[i], bf3, acc3[i][j], 0, 0, 0);
    }
    __syncthreads();
    cur ^= 1;
  }

  float bb1[4], bb3[4];
#pragma unroll
  for (int j = 0; j < 4; j++) {
    const int col = n0 + wn + j * 16 + ln;
    bb1[j] = B1[col]; bb3[j] = B3[col];
  }
#pragma unroll
  for (int i = 0; i < 4; i++) {
#pragma unroll
    for (int r = 0; r < 4; r++) {
      const int row = m0 + wm + i * 16 + q * 4 + r;  // D: row=quad*4+reg
      if (row >= count) continue;
      u16* ap = act + (size_t)(rowbase + row) * N + n0 + wn;
#pragma unroll
      for (int j = 0; j < 4; j++) {
        float h = acc1[i][j][r] + bb1[j];
        float g = acc3[i][j][r] + bb3[j];
        float sv = 1.f / (1.f + __expf(-h));
        ap[j * 16 + ln] = f2bf(h * sv * g);             // D: col=lane&15
      }
    }
  }
}

// ------- Down (MERGED): every block runs a uniform K=1408 loop --------------
// z = 0..NEXP-1: routed expert z -> Rbuf rows (acc + b2[e])
// z = NEXP+h (h=0,1): shared expert split-K half h -> Spart[h] (acc + sb2 if h==0)
// Shared down was 256 blocks = 1 block/CU standalone; merged+split-K it shares
// the machine with routed work and halves its serial K-chain.
__global__ __launch_bounds__(256, 2)
void ffn_down_m(const u16* __restrict__ A_act, const u16* __restrict__ S_act,
                const u16* __restrict__ w2t, const float* __restrict__ b2p,
                const u16* __restrict__ sw2t, const float* __restrict__ sb2,
                const int* __restrict__ offsets,
                float* __restrict__ Rbuf, float* __restrict__ Spart)
{
  const int z = blockIdx.z;
  int count, rowbase = 0, astride, koff;
  const u16 *Abase, *W2; const float* B2; float* outp; bool addBias; int ostride_base;
  if (z < NEXP) {
    rowbase = offsets[z]; count = offsets[z + 1] - rowbase;
    Abase = A_act; astride = INTER; koff = 0;
    W2 = w2t + (size_t)z * DIM * INTER;          // [DIM][INTER]
    B2 = b2p + (size_t)z * DIM; addBias = true;
    outp = Rbuf; ostride_base = rowbase;         // rows at rowbase+row
  } else {
    const int h = z - NEXP;
    count = T_TOKENS;
    Abase = S_act; astride = SINTER; koff = h * KD;
    W2 = sw2t;                                   // [DIM][SINTER]
    B2 = sb2; addBias = (h == 0);
    outp = Spart + (size_t)h * T_TOKENS * DIM; ostride_base = 0;
  }
  const int m0 = blockIdx.y * 128;
  if (m0 >= count) return;
  const int n0 = blockIdx.x * 128;

  __shared__ u16 sA[2][128 * 32];
  __shared__ u16 sB[2][128 * 32];

  const int tid = threadIdx.x;
  const int lane = tid & 63;
  const int w = tid >> 6;

  const int kc8 = (lane & 3) * 8;
  const u16* aptr[2]; const u16* bptr[2];
  int ldoff[2];
#pragma unroll
  for (int i = 0; i < 2; i++) {
    const int row = i * 64 + w * 16 + (lane >> 2);
    ldoff[i] = i * 2048 + w * 512 + lane * 8;
    int arow = m0 + row; if (arow > count - 1) arow = count - 1;
    aptr[i] = Abase + (size_t)(rowbase + arow) * astride + koff + kc8;
    bptr[i] = W2 + (size_t)(n0 + row) * astride + koff + kc8;  // W2 k-stride == astride
  }

  const int ln = lane & 15, q = lane >> 4;
  const int wm = (w & 1) * 64, wn = (w >> 1) * 64;
  const int paOff = (wm + ln) * 32 + q * 8;
  const int pbOff = (wn + ln) * 32 + q * 8;

  f4v acc[4][4] = {};

  auto stage = [&](int buf, int k0) {
#pragma unroll
    for (int i = 0; i < 2; i++) {
      load_lds16(aptr[i] + k0, &sA[buf][ldoff[i]]);
      load_lds16(bptr[i] + k0, &sB[buf][ldoff[i]]);
    }
  };

  stage(0, 0);
  __syncthreads();
  int cur = 0;
  for (int k0 = 32; k0 <= KD; k0 += 32) {        // uniform 44 steps, all blocks
    if (k0 < KD) stage(cur ^ 1, k0);

    const u16* pa = sA[cur] + paOff;
    const u16* pb = sB[cur] + pbOff;
    s8v af[4];
#pragma unroll
    for (int i = 0; i < 4; i++) af[i] = *(const s8v*)(pa + i * 512);
#pragma unroll
    for (int j = 0; j < 4; j++) {
      s8v bf = *(const s8v*)(pb + j * 512);
#pragma unroll
      for (int i = 0; i < 4; i++)
        acc[i][j] = __builtin_amdgcn_mfma_f32_16x16x32_bf16(af[i], bf, acc[i][j], 0, 0, 0);
    }
    __syncthreads();
    cur ^= 1;
  }

  float bb[4];
#pragma unroll
  for (int j = 0; j < 4; j++) bb[j] = addBias ? B2[n0 + wn + j * 16 + ln] : 0.f;

#pragma unroll
  for (int i = 0; i < 4; i++) {
#pragma unroll
    for (int r = 0; r < 4; r++) {
      const int row = m0 + wm + i * 16 + q * 4 + r;
      if (row >= count) continue;
      float* orow = outp + (size_t)(ostride_base + row) * DIM + n0 + wn;
#pragma unroll
      for (int j = 0; j < 4; j++)
        orow[j * 16 + ln] = acc[i][j][r] + bb[j];
    }
  }
}

// ---- Combine: out[t] = S0[t] + S1[t] + w0*R[s0] + w1*R[s1] (atomic-free) ---
__global__ __launch_bounds__(256)
void combine(const float* __restrict__ R, const float* __restrict__ Spart,
             const int* __restrict__ slot_of,
             const float* __restrict__ g_w, float* __restrict__ out)
{
  const int t = blockIdx.x;
  const int c = threadIdx.x * 4;
  const int s0 = slot_of[t * 2 + 0], s1 = slot_of[t * 2 + 1];
  const float w0 = g_w[t * 2 + 0],  w1 = g_w[t * 2 + 1];
  float4 a = *(const float4*)(R + (size_t)s0 * DIM + c);
  float4 b = *(const float4*)(R + (size_t)s1 * DIM + c);
  float4 p = *(const float4*)(Spart + (size_t)t * DIM + c);
  float4 qq = *(const float4*)(Spart + (size_t)(T_TOKENS + t) * DIM + c);
  float4 o;
  o.x = p.x + qq.x + w0 * a.x + w1 * b.x;
  o.y = p.y + qq.y + w0 * a.y + w1 * b.y;
  o.z = p.z + qq.z + w0 * a.z + w1 * b.z;
  o.w = p.w + qq.w + w0 * a.w + w1 * b.w;
  *(float4*)(out + (size_t)t * DIM + c) = o;
}

extern "C" void kernel_launch(void* const* d_in, const int* in_sizes, int n_in,
                              void* d_out, int out_size, void* d_ws, size_t ws_size,
                              hipStream_t stream)
{
  const float* x   = (const float*)d_in[0];
  const float* gw  = (const float*)d_in[1];
  const float* gb  = (const float*)d_in[2];
  const float* w1  = (const float*)d_in[3];
  const float* b1  = (const float*)d_in[4];
  const float* w3  = (const float*)d_in[5];
  const float* b3  = (const float*)d_in[6];
  const float* w2  = (const float*)d_in[7];
  const float* b2  = (const float*)d_in[8];
  const float* sw1 = (const float*)d_in[9];
  const float* sb1 = (const float*)d_in[10];
  const float* sw3 = (const float*)d_in[11];
  const float* sb3 = (const float*)d_in[12];
  const float* sw2 = (const float*)d_in[13];
  const float* sb2 = (const float*)d_in[14];
  float* out = (float*)d_out;

  char* ws = (char*)d_ws;
  size_t off = 0;
  auto alloc = [&](size_t bytes) -> char* {
    off = (off + 255) & ~(size_t)255;
    char* p = ws + off;
    off += bytes;
    return p;
  };
  int*   offsets  = (int*)  alloc((NEXP + 1) * 4);
  int*   g_e      = (int*)  alloc((size_t)T_TOKENS * 2 * 4);
  float* g_w      = (float*)alloc((size_t)T_TOKENS * 2 * 4);
  int*   tok_slot = (int*)  alloc((size_t)T_TOKENS * 2 * 4);
  int*   slot_of  = (int*)  alloc((size_t)T_TOKENS * 2 * 4);
  u16*   xbf      = (u16*)  alloc((size_t)T_TOKENS * DIM * 2);
  u16*   w1t      = (u16*)  alloc((size_t)NEXP * INTER * DIM * 2);
  u16*   w3t      = (u16*)  alloc((size_t)NEXP * INTER * DIM * 2);
  u16*   w2t      = (u16*)  alloc((size_t)NEXP * DIM * INTER * 2);
  u16*   sw1t     = (u16*)  alloc((size_t)SINTER * DIM * 2);
  u16*   sw3t     = (u16*)  alloc((size_t)SINTER * DIM * 2);
  u16*   sw2t     = (u16*)  alloc((size_t)DIM * SINTER * 2);
  u16*   A_act    = (u16*)  alloc((size_t)T_TOKENS * 2 * INTER * 2);
  u16*   S_act    = (u16*)  alloc((size_t)T_TOKENS * SINTER * 2);
  // Workspace-neutral partial buffers (proven-footprint aliasing):
  //   Rbuf  (32 MB) aliases w1t (46 MB) — w1t dead after ffn_up_m
  //   Spart (32 MB) aliases w3t (46 MB) — w3t dead after ffn_up_m
  // ffn_down_m (writer of both) runs strictly after ffn_up_m on this stream.
  float* Rbuf     = (float*)w1t;
  float* Spart    = (float*)w3t;
  (void)ws_size; (void)in_sizes; (void)n_in; (void)out_size;

  // ---- routing (atomic-free) ----
  gate_logits<<<T_TOKENS / 4, 256, 0, stream>>>(x, gw, gb, g_e, g_w);
  route_build<<<1, 256, 0, stream>>>(g_e, offsets, tok_slot, slot_of);

  // ---- weight/activation conversion (bf16, transposed to [N][K]) ----------
  cvt_x<<<(T_TOKENS * DIM) / (256 * 8), 256, 0, stream>>>(x, xbf);
  transpose_cvt2<<<dim3(INTER / 64, DIM / 64, 2 * NEXP), 256, 0, stream>>>(
      w1, w3, w1t, w3t, DIM, INTER);
  transpose_cvt<<<dim3(DIM / 64, INTER / 64, NEXP), 256, 0, stream>>>(w2, w2t, INTER, DIM);
  transpose_cvt2<<<dim3(SINTER / 64, DIM / 64, 2), 256, 0, stream>>>(
      sw1, sw3, sw1t, sw3t, DIM, SINTER);
  transpose_cvt<<<dim3(DIM / 64, SINTER / 64, 1), 256, 0, stream>>>(sw2, sw2t, SINTER, DIM);

  // ---- merged up: routed experts (z<16) + shared expert (z=16) ------------
  ffn_up_m<<<dim3(SINTER / 128, T_TOKENS / 128, NEXP + 1), 256, 0, stream>>>(
      xbf, w1t, b1, w3t, b3, sw1t, sb1, sw3t, sb3,
      offsets, tok_slot, A_act, S_act);

  // ---- merged down: routed (z<16) + shared split-K (z=16,17), uniform K ---
  ffn_down_m<<<dim3(DIM / 128, T_TOKENS / 128, NEXP + 2), 256, 0, stream>>>(
      A_act, S_act, w2t, b2, sw2t, sb2, offsets, Rbuf, Spart);

  // ---- final gather-combine writes out --------------------------------------
  combine<<<T_TOKENS, 256, 0, stream>>>(Rbuf, Spart, slot_of, g_w, out);
}